// Round 3
// baseline (349.784 us; speedup 1.0000x reference)
//
#include <hip/hip_runtime.h>
#include <hip/hip_bf16.h>
#include <cstdint>
#include <cstddef>

typedef __hip_bfloat16 bf16;
typedef __attribute__((ext_vector_type(4))) float f32x4;
typedef __attribute__((ext_vector_type(8))) short s16x8;

// ---- async global->LDS, 16B per lane. Dest is wave-uniform base + lane*16. ----
__device__ __forceinline__ void gload_lds16(const void* g, void* l) {
    __builtin_amdgcn_global_load_lds(
        (const __attribute__((address_space(1))) unsigned int*)g,
        (__attribute__((address_space(3))) unsigned int*)l,
        16, 0, 0);
}

// =======================================================================
// GEMM descriptor + core. C[m,n] = act(sum_k A[m,k]*B[n,k] + bias[n]) * Mul
// flags: bit0 tanh, bit1 mulw, bit2 f32out, bit3 nontemporal
// Tile 128x128x64, 256 thr = 4 waves, each wave 64x64.
// LDS: 16B chunks; slot (row,c) holds global chunk (row, c^(row&7)).
// =======================================================================
struct GA {
    const bf16* A; const bf16* B; const float* bias; const float* Mul;
    void* C; int M, N, K, ldc, gx, cnt, flags;
};

__device__ __forceinline__ void gemm_core(short* sA, short* sB, const GA& g,
                                          int bm, int bn)
{
    const int tid  = threadIdx.x;
    const int lane = tid & 63;
    const int wave = tid >> 6;
    const int wr = wave >> 1, wc = wave & 1;
    const int l15 = lane & 15, quad = lane >> 4;
    const int N = g.N, K = g.K;

    f32x4 acc[4][4];
#pragma unroll
    for (int i = 0; i < 4; ++i)
#pragma unroll
        for (int j = 0; j < 4; ++j)
            acc[i][j] = (f32x4){0.f, 0.f, 0.f, 0.f};

    for (int kt = 0; kt < K; kt += 64) {
#pragma unroll
        for (int j = 0; j < 4; ++j) {
            int S   = (wave * 4 + j) * 64 + lane;      // LDS chunk slot
            int row = S >> 3;
            int cc  = (S & 7) ^ (row & 7);             // swizzled source chunk
            gload_lds16(g.A + (size_t)(bm * 128 + row) * K + kt + cc * 8, &sA[S * 8]);
        }
#pragma unroll
        for (int j = 0; j < 4; ++j) {
            int S   = (wave * 4 + j) * 64 + lane;
            int row = S >> 3;
            int cc  = (S & 7) ^ (row & 7);
            int ng  = bn * 128 + row;
            ng = (ng < N) ? ng : (N - 1);              // harmless when N%128==0
            gload_lds16(g.B + (size_t)ng * K + kt + cc * 8, &sB[S * 8]);
        }
        asm volatile("s_waitcnt vmcnt(0)" ::: "memory");
        __syncthreads();

#pragma unroll
        for (int ks = 0; ks < 2; ++ks) {
            s16x8 afr[4], bfr[4];
#pragma unroll
            for (int i = 0; i < 4; ++i) {
                int r = wr * 64 + i * 16 + l15;
                int q = ks * 4 + quad;
                afr[i] = *(const s16x8*)&sA[(r * 8 + (q ^ (r & 7))) * 8];
            }
#pragma unroll
            for (int j = 0; j < 4; ++j) {
                int r = wc * 64 + j * 16 + l15;
                int q = ks * 4 + quad;
                bfr[j] = *(const s16x8*)&sB[(r * 8 + (q ^ (r & 7))) * 8];
            }
#pragma unroll
            for (int i = 0; i < 4; ++i)
#pragma unroll
                for (int j = 0; j < 4; ++j)
                    acc[i][j] = __builtin_amdgcn_mfma_f32_16x16x32_bf16(
                        afr[i], bfr[j], acc[i][j], 0, 0, 0);
        }
        __syncthreads();
    }

    const bool ftanh = g.flags & 1, fmul = g.flags & 2;
    const bool f32o  = g.flags & 4, fnt  = g.flags & 8;
    // ---- epilogue. C/D layout: col = lane&15, row = quad*4 + reg ----
#pragma unroll
    for (int j = 0; j < 4; ++j) {
        int colg = bn * 128 + wc * 64 + j * 16 + l15;
        if (colg >= N) continue;
        float bv = g.bias[colg];
#pragma unroll
        for (int i = 0; i < 4; ++i) {
            int row0 = bm * 128 + wr * 64 + i * 16 + quad * 4;
#pragma unroll
            for (int r = 0; r < 4; ++r) {
                float v = acc[i][j][r] + bv;
                if (ftanh) v = tanhf(v);
                if (fmul)  v *= g.Mul[(size_t)(row0 + r) * N + colg];
                size_t o = (size_t)(row0 + r) * g.ldc + colg;
                if (f32o) {
                    if (fnt) __builtin_nontemporal_store(v, (float*)g.C + o);
                    else     ((float*)g.C)[o] = v;
                } else {
                    ((bf16*)g.C)[o] = __float2bfloat16(v);
                }
            }
        }
    }
}

// Two GEMMs batched into one launch, partitioned by block range.
__global__ __launch_bounds__(256)
void gemm_multi(GA g0, GA g1)
{
    __shared__ short sA[128 * 64];
    __shared__ short sB[128 * 64];
    int b = blockIdx.x;
    if (b < g0.cnt) {
        gemm_core(sA, sB, g0, b / g0.gx, b % g0.gx);
    } else {
        b -= g0.cnt;
        gemm_core(sA, sB, g1, b / g1.gx, b % g1.gx);
    }
}

// =======================================================================
// Fused f32->bf16 conversion of all bf16 operands + gather(AGE_inx[Endx]).
// Segments by blockIdx: t | W_age | W_prjT | W_prjL | W_fc3 | gather rows.
// =======================================================================
__device__ __forceinline__ void cvt8(const float* s, bf16* d, int i, int n)
{
    if (i + 7 < n) {
        float4 a = *(const float4*)(s + i);
        float4 b = *(const float4*)(s + i + 4);
        d[i + 0] = __float2bfloat16(a.x); d[i + 1] = __float2bfloat16(a.y);
        d[i + 2] = __float2bfloat16(a.z); d[i + 3] = __float2bfloat16(a.w);
        d[i + 4] = __float2bfloat16(b.x); d[i + 5] = __float2bfloat16(b.y);
        d[i + 6] = __float2bfloat16(b.z); d[i + 7] = __float2bfloat16(b.w);
    } else {
        for (int k = i; k < n; ++k) d[k] = __float2bfloat16(s[k]);
    }
}

__global__ __launch_bounds__(256)
void cvt_all(const float* __restrict__ t_in,   bf16* __restrict__ tb,
             const float* __restrict__ W_age,  bf16* __restrict__ Wageb,
             const float* __restrict__ W_prjT, bf16* __restrict__ WpTb,
             const float* __restrict__ W_prjL, bf16* __restrict__ WpLb,
             const float* __restrict__ W_fc3,  bf16* __restrict__ Wfc3b,
             const float* __restrict__ AGEinx, const int* __restrict__ Endx,
             bf16* __restrict__ AGEg)
{
    int b = blockIdx.x, tid = threadIdx.x;
    if (b < 3072)      { cvt8(t_in,   tb,    (b * 256 + tid) * 8, 8192 * 768); return; }
    b -= 3072;
    if (b < 288)       { cvt8(W_age,  Wageb, (b * 256 + tid) * 8, 768 * 768);  return; }
    b -= 288;
    if (b < 96)        { cvt8(W_prjT, WpTb,  (b * 256 + tid) * 8, 256 * 768);  return; }
    b -= 96;
    if (b < 96)        { cvt8(W_prjL, WpLb,  (b * 256 + tid) * 8, 256 * 768);  return; }
    b -= 96;
    if (b < 7)         { cvt8(W_fc3,  Wfc3b, (b * 256 + tid) * 8, 50 * 256);   return; }
    b -= 7;
    // gather: one row per block, threads 0..191 convert float4 each
    {
        int r = Endx[b];
        const float* s = AGEinx + (size_t)r * 768;
        bf16* d = AGEg + (size_t)b * 768;
        int c = tid * 4;
        if (c < 768) {
            float4 v = *(const float4*)(s + c);
            d[c + 0] = __float2bfloat16(v.x);
            d[c + 1] = __float2bfloat16(v.y);
            d[c + 2] = __float2bfloat16(v.z);
            d[c + 3] = __float2bfloat16(v.w);
        }
    }
}

// =======================================================================
// lintrans rows: z[row,:768] (fp32) -> minmax scale -> L2 norm -> bf16
// =======================================================================
__global__ __launch_bounds__(256)
void lintrans_k(const float* __restrict__ z, bf16* __restrict__ out)
{
    __shared__ float rmin[4], rmax[4], rsum[4];
    const int row  = blockIdx.x;
    const int tid  = threadIdx.x;
    const int lane = tid & 63;
    const int wave = tid >> 6;
    const float* zr = z + (size_t)row * 768;

    float v0 = zr[tid], v1 = zr[tid + 256], v2 = zr[tid + 512];
    float mn = fminf(fminf(v0, v1), v2);
    float mx = fmaxf(fmaxf(v0, v1), v2);
#pragma unroll
    for (int o = 32; o > 0; o >>= 1) {
        mn = fminf(mn, __shfl_down(mn, o));
        mx = fmaxf(mx, __shfl_down(mx, o));
    }
    if (lane == 0) { rmin[wave] = mn; rmax[wave] = mx; }
    __syncthreads();
    float bmn = fminf(fminf(rmin[0], rmin[1]), fminf(rmin[2], rmin[3]));
    float bmx = fmaxf(fmaxf(rmax[0], rmax[1]), fmaxf(rmax[2], rmax[3]));
    float sc  = 1.f / (bmx - bmn);
    v0 = (v0 - bmn) * sc; v1 = (v1 - bmn) * sc; v2 = (v2 - bmn) * sc;
    float s = v0 * v0 + v1 * v1 + v2 * v2;
#pragma unroll
    for (int o = 32; o > 0; o >>= 1) s += __shfl_down(s, o);
    if (lane == 0) rsum[wave] = s;
    __syncthreads();
    float tot = rsum[0] + rsum[1] + rsum[2] + rsum[3];
    float inv = 1.f / fmaxf(sqrtf(tot), 1e-12f);
    out[(size_t)row * 768 + tid]       = __float2bfloat16(v0 * inv);
    out[(size_t)row * 768 + tid + 256] = __float2bfloat16(v1 * inv);
    out[(size_t)row * 768 + tid + 512] = __float2bfloat16(v2 * inv);
}

// =======================================================================
extern "C" void kernel_launch(void* const* d_in, const int* in_sizes, int n_in,
                              void* d_out, int out_size, void* d_ws, size_t ws_size,
                              hipStream_t stream)
{
    (void)in_sizes; (void)n_in; (void)out_size; (void)ws_size;

    const float* t_in   = (const float*)d_in[0];   // [8192,768]
    const float* AGEinx = (const float*)d_in[1];   // [20000,768]
    const int*   Endx   = (const int*)  d_in[2];   // [4096]
    const float* W_age  = (const float*)d_in[3];   // [768,768]
    const float* b_age  = (const float*)d_in[4];   // [768]
    const float* W_prjT = (const float*)d_in[5];   // [256,768]
    const float* b_prjT = (const float*)d_in[6];   // [256]
    const float* W_prjL = (const float*)d_in[7];   // [256,768]
    const float* b_prjL = (const float*)d_in[8];   // [256]
    const float* outW   = (const float*)d_in[9];   // [4096,256]
    const float* outb   = (const float*)d_in[10];  // [4096]
    const float* W_fc3  = (const float*)d_in[11];  // [50,256]
    const float* b_fc3  = (const float*)d_in[12];  // [50]

    char* ws = (char*)d_ws;
    size_t off = 0;
    float* z    = (float*)(ws + off); off += (size_t)4096 * 768 * 4;
    bf16*  h    = (bf16*)(ws + off);  off += (size_t)8192 * 256 * 2;
    bf16*  tb   = (bf16*)(ws + off);  off += (size_t)8192 * 768 * 2;
    bf16*  AGEg = (bf16*)(ws + off);  off += (size_t)4096 * 768 * 2;
    bf16* Wageb = (bf16*)(ws + off);  off += (size_t)768 * 768 * 2;
    bf16* WpTb  = (bf16*)(ws + off);  off += (size_t)256 * 768 * 2;
    bf16* WpLb  = (bf16*)(ws + off);  off += (size_t)256 * 768 * 2;
    bf16* Wfc3b = (bf16*)(ws + off);  off += (size_t)50 * 256 * 2 + 64;
    bf16* AGE_E = (bf16*)(ws + off);  off += (size_t)4096 * 768 * 2;
    bf16* E2    = (bf16*)(ws + off);  off += (size_t)4096 * 256 * 2;

    float* o_c = (float*)d_out;                    // [8192,4096]
    float* o_f = o_c + (size_t)8192 * 4096;        // [8192,50]

    // K1: all conversions + gather (3072+288+96+96+7+4096 = 7655 blocks)
    cvt_all<<<7655, 256, 0, stream>>>(t_in, tb, W_age, Wageb, W_prjT, WpTb,
                                      W_prjL, WpLb, W_fc3, Wfc3b,
                                      AGEinx, Endx, AGEg);

    // K2: gemm1 (z = AGEg@W_age^T + b_age, f32 out) || gemm4 (h = tanh(t@W_prjT^T+b))
    GA g1 = { AGEg, Wageb, b_age, nullptr, z, 4096, 768, 768, 768, 6, 192, 4 };
    GA g4 = { tb, WpTb, b_prjT, nullptr, h, 8192, 256, 768, 256, 2, 128, 1 };
    gemm_multi<<<192 + 128, 256, 0, stream>>>(g1, g4);

    // K3: AGE_E = lintrans(z)
    lintrans_k<<<4096, 256, 0, stream>>>(z, AGE_E);

    // K4: gemm3 (E2 = tanh(AGE_E@W_prjL^T+b)*outW) || gemm6 (o_f = h@W_fc3^T+b, f32)
    GA g3 = { AGE_E, WpLb, b_prjL, outW, E2, 4096, 256, 768, 256, 2, 64, 3 };
    GA g6 = { h, Wfc3b, b_fc3, nullptr, o_f, 8192, 50, 256, 50, 1, 64, 4 };
    gemm_multi<<<64 + 64, 256, 0, stream>>>(g3, g6);

    // K5: gemm5 (o_c = h@E2^T + outb, f32 out, nontemporal)
    GA g5 = { h, E2, outb, nullptr, o_c, 8192, 4096, 256, 4096, 32, 2048, 4 | 8 };
    GA gz = { nullptr, nullptr, nullptr, nullptr, nullptr, 0, 0, 0, 1, 1, 0, 0 };
    gemm_multi<<<2048, 256, 0, stream>>>(g5, gz);
}